// Round 6
// baseline (210.090 us; speedup 1.0000x reference)
//
#include <hip/hip_runtime.h>
#include <stdint.h>

#define PARTITIONABLE 1

constexpr int V  = 32000;  // vocab
constexpr int F  = 200;    // VOCAB_FACTOR (outer)
constexpr int C  = 160;    // VOCAB_CHUNK  (inner)
constexpr int NT = 512;    // threads per block (8 waves)

constexpr float LOG2E = 1.4426950408889634f;
constexpr float SHIFT = 64.0f;   // constant exp2 bias; safe for |logit| < ~80
constexpr float LN2   = 0.6931471805599453f;

__device__ __forceinline__ uint32_t rotl32(uint32_t x, uint32_t r) {
  return (x << r) | (x >> (32u - r));
}

// JAX threefry2x32 primitive (5 groups of 4 rounds).
__device__ __forceinline__ void threefry2x32(uint32_t ka, uint32_t kb,
                                             uint32_t x0, uint32_t x1,
                                             uint32_t& o0, uint32_t& o1) {
  const uint32_t ks2 = ka ^ kb ^ 0x1BD11BDAu;
  x0 += ka; x1 += kb;
#define TF_R4(a,b,c,d) \
  x0 += x1; x1 = rotl32(x1, a); x1 ^= x0; \
  x0 += x1; x1 = rotl32(x1, b); x1 ^= x0; \
  x0 += x1; x1 = rotl32(x1, c); x1 ^= x0; \
  x0 += x1; x1 = rotl32(x1, d); x1 ^= x0;
  TF_R4(13,15,26,6)  x0 += kb;  x1 += ks2 + 1u;
  TF_R4(17,29,16,24) x0 += ks2; x1 += ka  + 2u;
  TF_R4(13,15,26,6)  x0 += ka;  x1 += kb  + 3u;
  TF_R4(17,29,16,24) x0 += kb;  x1 += ks2 + 4u;
  TF_R4(13,15,26,6)  x0 += ks2; x1 += ka  + 5u;
#undef TF_R4
  o0 = x0; o1 = x1;
}

// JAX random_bits(key, 32, shape)[idx]
__device__ __forceinline__ uint32_t rand_bits(uint32_t ka, uint32_t kb, uint32_t idx) {
  uint32_t o0, o1;
  threefry2x32(ka, kb, 0u, idx, o0, o1);   // counts1=hi(idx)=0, counts2=lo(idx)
  return o0 ^ o1;                          // 32-bit path: bits1 ^ bits2
}

// jax.random.gumbel: -log(-log(uniform(tiny, 1)))  (exact logf for RNG fidelity)
__device__ __forceinline__ float bits_to_gumbel(uint32_t bits) {
  float u = __uint_as_float((bits >> 9) | 0x3f800000u) - 1.0f;
  u = fmaxf(u, 1.1754943508222875e-38f);
  return -logf(-logf(u));
}

// Pack (value, index) so u64 max == (max value, then min index): first-index
// tie-break like jnp.argmax. Order-independent integer max.
__device__ __forceinline__ unsigned long long pack_max(float z, int idx) {
  uint32_t ub = __float_as_uint(z);
  ub = (ub & 0x80000000u) ? ~ub : (ub | 0x80000000u);
  return ((unsigned long long)ub << 32) | (uint32_t)(0xFFFFFFFFu - (uint32_t)idx);
}

__device__ __forceinline__ void derive_keys(uint32_t& k1a, uint32_t& k1b,
                                            uint32_t& k2a, uint32_t& k2b) {
  // split(key(42)) foldlike: key_i = threefry((0,42), (0,i)). Constant-folded.
  threefry2x32(0u, 42u, 0u, 0u, k1a, k1b);
  threefry2x32(0u, 42u, 0u, 1u, k2a, k2b);
}

// ---------------- Kernel A: pure stream — per-chunk raw exp2 sums ------------
// 8-lane group per chunk-task; grid-stride; no LDS, no barriers, no tail.
__global__ __launch_bounds__(NT)
void stream_kernel(const float* __restrict__ logits, float* __restrict__ css,
                   int n_tasks) {
  const int gl      = threadIdx.x & 7;
  const int grp     = (blockIdx.x * NT + threadIdx.x) >> 3;
  const int n_grps  = (gridDim.x * NT) >> 3;
  for (int task = grp; task < n_tasks; task += n_grps) {
    const int row = task / F;              // const-div -> magic mul
    const int c   = task - row * F;
    const float4* cp4 = (const float4*)(logits + (size_t)row * V + c * C);
    float4 w[5];
#pragma unroll
    for (int j = 0; j < 5; ++j) w[j] = cp4[gl + 8 * j];
    float s = 0.f;
#pragma unroll
    for (int j = 0; j < 5; ++j) {
      s += __builtin_amdgcn_exp2f(fmaf(w[j].x, LOG2E, -SHIFT));
      s += __builtin_amdgcn_exp2f(fmaf(w[j].y, LOG2E, -SHIFT));
      s += __builtin_amdgcn_exp2f(fmaf(w[j].z, LOG2E, -SHIFT));
      s += __builtin_amdgcn_exp2f(fmaf(w[j].w, LOG2E, -SHIFT));
    }
#pragma unroll
    for (int o = 4; o; o >>= 1) s += __shfl_xor(s, o);   // within 8-lane group
    if (gl == 0) css[task] = s;
  }
}

// ---------------- Kernel B: one wave per row — both sampling stages ----------
__global__ __launch_bounds__(NT)
void sample_kernel(const float* __restrict__ logits, const float* __restrict__ css,
                   int* __restrict__ out, int n_rows) {
  const int lane = threadIdx.x & 63;
  const int row  = blockIdx.x * (NT / 64) + (threadIdx.x >> 6);
  if (row >= n_rows) return;

  uint32_t k1a, k1b, k2a, k2b;
  derive_keys(k1a, k1b, k2a, k2b);

  // load this row's 200 chunk sums: lanes 0..49 read one float4 each (800 B)
  float4 c4 = make_float4(0.f, 0.f, 0.f, 0.f);
  if (lane < 50) c4 = ((const float4*)(css + (size_t)row * F))[lane];

  // S = sum (lane-local then fixed 6-step butterfly => deterministic)
  float S = (c4.x + c4.y) + (c4.z + c4.w);
#pragma unroll
  for (int o = 32; o; o >>= 1) S += __shfl_xor(S, o);

  // stage 1: outer = argmax_f( log(cs[f]/S) + gumbel(k1)[row*F+f] )
  unsigned long long best = 0ull;
  if (lane < 50) {
    const float cs[4] = {c4.x, c4.y, c4.z, c4.w};
#pragma unroll
    for (int k = 0; k < 4; ++k) {
      int f = lane * 4 + k;
      float z = logf(cs[k] / S) +
                bits_to_gumbel(rand_bits(k1a, k1b, (uint32_t)(row * F + f)));
      unsigned long long p = pack_max(z, f);
      best = (p > best) ? p : best;
    }
  }
#pragma unroll
  for (int o = 32; o; o >>= 1) {
    unsigned long long q = __shfl_xor(best, o);
    best = (q > best) ? q : best;
  }
  const int outer = (int)(0xFFFFFFFFu - (uint32_t)(best & 0xFFFFFFFFull));

  // stage 2: log(p) = v - lnZ;  lnZ = log(Sraw) + 64*ln2 (row max cancels)
  const float lnZ = logf(S) + SHIFT * LN2;
  unsigned long long best2 = 0ull;
  if (lane < 40) {
    float4 v4 = ((const float4*)(logits + (size_t)row * V + outer * C))[lane];
    const float v[4] = {v4.x, v4.y, v4.z, v4.w};
#pragma unroll
    for (int k = 0; k < 4; ++k) {
      int c = lane * 4 + k;
      float z = (v[k] - lnZ) +
                bits_to_gumbel(rand_bits(k2a, k2b, (uint32_t)(row * C + c)));
      unsigned long long p = pack_max(z, c);
      best2 = (p > best2) ? p : best2;
    }
  }
#pragma unroll
  for (int o = 32; o; o >>= 1) {
    unsigned long long q = __shfl_xor(best2, o);
    best2 = (q > best2) ? q : best2;
  }
  if (lane == 0) {
    int inner = (int)(0xFFFFFFFFu - (uint32_t)(best2 & 0xFFFFFFFFull));
    out[row] = C * outer + inner;
  }
}

// ---------------- Fused fallback (round-5 kernel) if ws is too small ---------
__global__ __launch_bounds__(NT)
void fused_kernel(const float* __restrict__ logits, int* __restrict__ out) {
  const int row = blockIdx.x;
  const float* rp = logits + (size_t)row * V;
  const int t    = threadIdx.x;
  const int lane = t & 63;
  const int wid  = t >> 6;

  __shared__ float css[F];
  __shared__ float wred[NT / 64];
  __shared__ unsigned long long amax1, amax2;
  if (t == 0) { amax1 = 0ull; amax2 = 0ull; }

  uint32_t k1a, k1b, k2a, k2b;
  derive_keys(k1a, k1b, k2a, k2b);

  const int g  = t >> 3;
  const int gl = t & 7;
  for (int c = g; c < F; c += NT / 8) {
    const float4* cp4 = (const float4*)(rp + c * C);
    float4 w[5];
#pragma unroll
    for (int j = 0; j < 5; ++j) w[j] = cp4[gl + 8 * j];
    float s = 0.f;
#pragma unroll
    for (int j = 0; j < 5; ++j) {
      s += __builtin_amdgcn_exp2f(fmaf(w[j].x, LOG2E, -SHIFT));
      s += __builtin_amdgcn_exp2f(fmaf(w[j].y, LOG2E, -SHIFT));
      s += __builtin_amdgcn_exp2f(fmaf(w[j].z, LOG2E, -SHIFT));
      s += __builtin_amdgcn_exp2f(fmaf(w[j].w, LOG2E, -SHIFT));
    }
#pragma unroll
    for (int o = 4; o; o >>= 1) s += __shfl_xor(s, o);
    if (gl == 0) css[c] = s;
  }
  __syncthreads();

  float myCs = (t < F) ? css[t] : 0.f;
  {
    float v = myCs;
#pragma unroll
    for (int o = 32; o; o >>= 1) v += __shfl_xor(v, o);
    if (lane == 0) wred[wid] = v;
  }
  __syncthreads();
  float S = wred[0];
#pragma unroll
  for (int w = 1; w < NT / 64; ++w) S += wred[w];

  if (t < F) {
    float l1 = logf(myCs / S);
    float gu = bits_to_gumbel(rand_bits(k1a, k1b, (uint32_t)(row * F + t)));
    atomicMax(&amax1, pack_max(l1 + gu, t));
  }
  __syncthreads();
  const int outer = (int)(0xFFFFFFFFu - (uint32_t)(amax1 & 0xFFFFFFFFull));

  if (t < C) {
    float v   = rp[outer * C + t];
    float lnZ = logf(S) + SHIFT * LN2;
    float gu  = bits_to_gumbel(rand_bits(k2a, k2b, (uint32_t)(row * C + t)));
    atomicMax(&amax2, pack_max((v - lnZ) + gu, t));
  }
  __syncthreads();
  if (t == 0) {
    int inner = (int)(0xFFFFFFFFu - (uint32_t)(amax2 & 0xFFFFFFFFull));
    out[row] = C * outer + inner;
  }
}

extern "C" void kernel_launch(void* const* d_in, const int* in_sizes, int n_in,
                              void* d_out, int out_size, void* d_ws, size_t ws_size,
                              hipStream_t stream) {
  const float* logits = (const float*)d_in[0];
  int* out = (int*)d_out;
  const int N = in_sizes[0] / V;                 // 8192 rows
  const size_t need = (size_t)N * F * sizeof(float);
  if (ws_size >= need) {
    float* css = (float*)d_ws;
    stream_kernel<<<1024, NT, 0, stream>>>(logits, css, N * F);
    sample_kernel<<<(N + NT / 64 - 1) / (NT / 64), NT, 0, stream>>>(logits, css, out, N);
  } else {
    fused_kernel<<<N, NT, 0, stream>>>(logits, out);
  }
}

// Round 7
// 179.108 us; speedup vs baseline: 1.1730x; 1.1730x over previous
//
#include <hip/hip_runtime.h>
#include <stdint.h>

#define PARTITIONABLE 1

constexpr int V  = 32000;  // vocab
constexpr int F  = 200;    // VOCAB_FACTOR (outer)
constexpr int C  = 160;    // VOCAB_CHUNK  (inner)
constexpr int NT = 512;    // threads per block (8 waves)

constexpr float LOG2E = 1.4426950408889634f;
constexpr float SHIFT = 64.0f;   // constant exp2 bias; safe for |logit| < ~80
constexpr float LN2   = 0.6931471805599453f;

__device__ __forceinline__ uint32_t rotl32(uint32_t x, uint32_t r) {
  return (x << r) | (x >> (32u - r));
}

// JAX threefry2x32 primitive (5 groups of 4 rounds).
__device__ __forceinline__ void threefry2x32(uint32_t ka, uint32_t kb,
                                             uint32_t x0, uint32_t x1,
                                             uint32_t& o0, uint32_t& o1) {
  const uint32_t ks2 = ka ^ kb ^ 0x1BD11BDAu;
  x0 += ka; x1 += kb;
#define TF_R4(a,b,c,d) \
  x0 += x1; x1 = rotl32(x1, a); x1 ^= x0; \
  x0 += x1; x1 = rotl32(x1, b); x1 ^= x0; \
  x0 += x1; x1 = rotl32(x1, c); x1 ^= x0; \
  x0 += x1; x1 = rotl32(x1, d); x1 ^= x0;
  TF_R4(13,15,26,6)  x0 += kb;  x1 += ks2 + 1u;
  TF_R4(17,29,16,24) x0 += ks2; x1 += ka  + 2u;
  TF_R4(13,15,26,6)  x0 += ka;  x1 += kb  + 3u;
  TF_R4(17,29,16,24) x0 += kb;  x1 += ks2 + 4u;
  TF_R4(13,15,26,6)  x0 += ks2; x1 += ka  + 5u;
#undef TF_R4
  o0 = x0; o1 = x1;
}

// JAX random_bits(key, 32, shape)[idx] (partitionable path)
__device__ __forceinline__ uint32_t rand_bits(uint32_t ka, uint32_t kb, uint32_t idx) {
  uint32_t o0, o1;
  threefry2x32(ka, kb, 0u, idx, o0, o1);   // counts1=hi(idx)=0, counts2=lo(idx)
  return o0 ^ o1;                          // 32-bit path: bits1 ^ bits2
}

// jax.random.gumbel: -log(-log(uniform(tiny, 1)))  (exact logf for RNG fidelity)
__device__ __forceinline__ float bits_to_gumbel(uint32_t bits) {
  float u = __uint_as_float((bits >> 9) | 0x3f800000u) - 1.0f;
  u = fmaxf(u, 1.1754943508222875e-38f);
  return -logf(-logf(u));
}

// Pack (value, index) so u64 max == (max value, then min index): first-index
// tie-break like jnp.argmax. Integer atomicMax => order-independent =>
// deterministic across graph replays.
__device__ __forceinline__ unsigned long long pack_max(float z, int idx) {
  uint32_t ub = __float_as_uint(z);
  ub = (ub & 0x80000000u) ? ~ub : (ub | 0x80000000u);
  return ((unsigned long long)ub << 32) | (uint32_t)(0xFFFFFFFFu - (uint32_t)idx);
}

// Raw chunk exp2-sum for chunk c, shared across the 8-lane group.
// (fma + exp2 + add = 3 VALU/element; constant bias, no max needed.)
__device__ __forceinline__ float chunk_sum(const float* __restrict__ rp,
                                           int c, int gl) {
  const float4* cp4 = (const float4*)(rp + c * C);
  float4 w[5];
#pragma unroll
  for (int j = 0; j < 5; ++j) w[j] = cp4[gl + 8 * j];
  float s = 0.f;
#pragma unroll
  for (int j = 0; j < 5; ++j) {
    s += __builtin_amdgcn_exp2f(fmaf(w[j].x, LOG2E, -SHIFT));
    s += __builtin_amdgcn_exp2f(fmaf(w[j].y, LOG2E, -SHIFT));
    s += __builtin_amdgcn_exp2f(fmaf(w[j].z, LOG2E, -SHIFT));
    s += __builtin_amdgcn_exp2f(fmaf(w[j].w, LOG2E, -SHIFT));
  }
#pragma unroll
  for (int o = 4; o; o >>= 1) s += __shfl_xor(s, o);   // within 8-lane group
  return s;
}

__global__ __launch_bounds__(NT)
void sampler_kernel(const float* __restrict__ logits, int* __restrict__ out) {
  const int row = blockIdx.x;
  const float* rp = logits + (size_t)row * V;
  const int t    = threadIdx.x;
  const int lane = t & 63;
  const int wid  = t >> 6;

  __shared__ float css[F];        // raw chunk sums: sum_chunk 2^(v*log2e - 64)
  __shared__ float wred[NT / 64]; // per-wave reduction partials
  __shared__ unsigned long long amax1, amax2;

  if (t == 0) { amax1 = 0ull; amax2 = 0ull; }

  // --- derive k1, k2 from seed 42 (all-literal => constant-folded) ---
  uint32_t k1a, k1b, k2a, k2b;
  threefry2x32(0u, 42u, 0u, 0u, k1a, k1b);  // split foldlike: threefry((0,42),(0,i))
  threefry2x32(0u, 42u, 0u, 1u, k2a, k2b);

  // ---- single pass: per-chunk raw exp2 sums; 8-lane group per chunk.
  //      Wave-balanced schedule: every group does chunks {g, g+64, g+128};
  //      the 8 leftover chunks (192..199) go to one group PER WAVE
  //      (g % 8 == 0 -> chunk 192 + g/8), so all 8 waves stream exactly
  //      25 chunks — no wave idles at the barrier behind a heavy wave 0.
  const int g  = t >> 3;   // 0..63
  const int gl = t & 7;
#pragma unroll
  for (int r = 0; r < 3; ++r) {
    const int c = g + r * 64;
    float s = chunk_sum(rp, c, gl);
    if (gl == 0) css[c] = s;
  }
  if ((g & 7) == 0) {
    const int c = 192 + (g >> 3);
    float s = chunk_sum(rp, c, gl);
    if (gl == 0) css[c] = s;
  }
  __syncthreads();

  // ---- S = sum_f css[f]  (wave-shuffle, fixed order => deterministic) ----
  float myCs = (t < F) ? css[t] : 0.f;
  {
    float v = myCs;
#pragma unroll
    for (int o = 32; o; o >>= 1) v += __shfl_xor(v, o);
    if (lane == 0) wred[wid] = v;
  }
  __syncthreads();
  float S = wred[0];
#pragma unroll
  for (int w = 1; w < NT / 64; ++w) S += wred[w];

  // ---- stage 1: outer = argmax_f( log(cs[f]/S) + gumbel(k1)[row*F+f] ) ----
  // (2^-64 and e^rowmax scale factors cancel in the ratio.)
  if (t < F) {
    float l1 = logf(myCs / S);
    float gu = bits_to_gumbel(rand_bits(k1a, k1b, (uint32_t)(row * F + t)));
    atomicMax(&amax1, pack_max(l1 + gu, t));
  }
  __syncthreads();
  const int outer = (int)(0xFFFFFFFFu - (uint32_t)(amax1 & 0xFFFFFFFFull));

  // ---- stage 2: log(p) = v - (log(Sraw) + 64*ln2); row max cancels exactly ----
  if (t < C) {
    float v   = rp[outer * C + t];      // re-read selected chunk only (640 B)
    float lnZ = logf(S) + SHIFT * LN2;  // == rowmax + log(sum e^(v-rowmax))
    float gu  = bits_to_gumbel(rand_bits(k2a, k2b, (uint32_t)(row * C + t)));
    atomicMax(&amax2, pack_max((v - lnZ) + gu, t));
  }
  __syncthreads();
  if (t == 0) {
    int inner = (int)(0xFFFFFFFFu - (uint32_t)(amax2 & 0xFFFFFFFFull));
    out[row] = C * outer + inner;
  }
}

extern "C" void kernel_launch(void* const* d_in, const int* in_sizes, int n_in,
                              void* d_out, int out_size, void* d_ws, size_t ws_size,
                              hipStream_t stream) {
  const float* logits = (const float*)d_in[0];
  int* out = (int*)d_out;
  const int N = in_sizes[0] / V;  // 8192 rows
  sampler_kernel<<<N, NT, 0, stream>>>(logits, out);
}